// Round 13
// baseline (148.629 us; speedup 1.0000x reference)
//
#include <hip/hip_runtime.h>
#include <math.h>

#define GENES 20000
#define LEVEL 10000
#define STEPS 7
#define DEG   16
#define EPSZ  (LEVEL * DEG)
#define CCOLS 32             // batch cols per step1 chunk
#define NCHUNK 8             // step1 chunks == XCDs
#define DBLK  313            // step1 blocks per chunk (32 dests each)
#define NGT   625            // gene tiles (20000/32)
#define MSTRIDE 18           // step1 LDS metadata stride
#define SCOLS 8              // staged colchunk width (bf16)
#define NCC   32             // colchunks = 256 cols / 8
#define GPB   8              // blocks per colchunk (staged)
#define DPB   1250           // dests per staged block

typedef unsigned short bf8 __attribute__((ext_vector_type(8)));

__device__ inline float bf2f(unsigned short u) {
    union { unsigned u; float f; } c; c.u = ((unsigned)u) << 16; return c.f;
}
__device__ inline unsigned short f2bf(float x) {     // round-to-nearest-even
    union { float f; unsigned u; } c; c.f = x;
    return (unsigned short)((c.u + 0x7fffu + ((c.u >> 16) & 1u)) >> 16);
}

// ---------------------------------------------------------------------------
// Metadata prep: for steps k=1..6, srcT[kk][e][d] = src[k][d*16+e] - base (u16),
// wT[kk][e][d] = edge_weight[k][d*16+e]. Coalesced read + coalesced write via LDS.
// Bounds-guarded: block 39 covers only dests 9984..9999.
// ---------------------------------------------------------------------------
__global__ __launch_bounds__(256) void prep_k(const int*   __restrict__ src,
                                              const float* __restrict__ ew,
                                              unsigned short* __restrict__ srcT,
                                              float*          __restrict__ wT) {
    const int kk = blockIdx.y;               // 0..5  (step k = kk+1)
    const int b  = blockIdx.x;               // 0..39 (256 dests each)
    const int t  = threadIdx.x;
    const int base = GENES + kk * LEVEL;
    __shared__ unsigned short s_i[256][DEG + 1];
    __shared__ float          s_w[256][DEG + 1];
    const int*   sk = src + (size_t)(kk + 1) * EPSZ + (size_t)b * 256 * DEG;
    const float* wk = ew  + (size_t)(kk + 1) * EPSZ + (size_t)b * 256 * DEG;
    const int lim4 = (EPSZ - b * 256 * DEG) / 4;   // remaining int4s in this step
#pragma unroll
    for (int i = 0; i < 4; ++i) {
        const int m4 = i * 256 + t;          // int4 index (0..1023)
        if (m4 >= lim4) continue;
        const int4   sv = reinterpret_cast<const int4*>(sk)[m4];
        const float4 wv = reinterpret_cast<const float4*>(wk)[m4];
        const int dl = m4 >> 2, e0 = (m4 & 3) * 4;
        s_i[dl][e0 + 0] = (unsigned short)(sv.x - base);
        s_i[dl][e0 + 1] = (unsigned short)(sv.y - base);
        s_i[dl][e0 + 2] = (unsigned short)(sv.z - base);
        s_i[dl][e0 + 3] = (unsigned short)(sv.w - base);
        s_w[dl][e0 + 0] = wv.x;
        s_w[dl][e0 + 1] = wv.y;
        s_w[dl][e0 + 2] = wv.z;
        s_w[dl][e0 + 3] = wv.w;
    }
    __syncthreads();
    const int dg = b * 256;
    if (dg + t < LEVEL) {
#pragma unroll
        for (int e = 0; e < DEG; ++e) {
            srcT[((size_t)kk * DEG + e) * LEVEL + dg + t] = s_i[t][e];
            wT  [((size_t)kk * DEG + e) * LEVEL + dg + t] = s_w[t][e];
        }
    }
}

// ---------------------------------------------------------------------------
// Transpose X[b][g] -> XT[8 chunks][20000][32] bf16 (step1 source layout).
// ---------------------------------------------------------------------------
__global__ __launch_bounds__(256) void transpose_k(const float* __restrict__ X,
                                                   const int*   __restrict__ gene_map,
                                                   unsigned short* __restrict__ XT) {
    __shared__ float tile[32][33];
    const int chunk = blockIdx.x;
    const int l4  = threadIdx.x & 7;
    const int r8  = threadIdx.x >> 3;
    const int lo  = threadIdx.x & 31;
    const int gr8 = threadIdx.x >> 5;
    unsigned short* XTp = XT + (size_t)chunk * GENES * CCOLS;
    for (int i = 0; i < 4; ++i) {
        const int gt = blockIdx.y * 4 + i;
        if (gt >= NGT) break;
        const int g0 = gt * 32;
        if (i) __syncthreads();
        const float4 xv = *reinterpret_cast<const float4*>(
            X + (size_t)(chunk * CCOLS + r8) * GENES + g0 + l4 * 4);
        tile[r8][l4 * 4 + 0] = xv.x;
        tile[r8][l4 * 4 + 1] = xv.y;
        tile[r8][l4 * 4 + 2] = xv.z;
        tile[r8][l4 * 4 + 3] = xv.w;
        __syncthreads();
#pragma unroll
        for (int jj = 0; jj < 4; ++jj) {
            const int gr   = gr8 + jj * 8;
            const int node = gene_map[g0 + gr];
            XTp[(size_t)node * CCOLS + lo] = f2bf(tile[lo][gr]);
        }
    }
}

// ---------------------------------------------------------------------------
// Step 1 (k=0, genes source too big for LDS): r11 gather kernel, but stores
// into the NEW staged layout hcur[32 colchunks][10000][8]; colchunk=chunk*4+c2.
// ---------------------------------------------------------------------------
__global__ __launch_bounds__(256) void step1_k(const unsigned short* __restrict__ hprev,
                                               unsigned short*       __restrict__ hcur,
                                               const int*   __restrict__ src_k,
                                               const float* __restrict__ w_k,
                                               const float* __restrict__ node_bias,
                                               const int*   __restrict__ dstu_k) {
    const int bid   = blockIdx.x;
    const int chunk = bid & 7;
    const int cb    = bid >> 3;                // 0..312
    const int tid   = threadIdx.x;

    __shared__ int   s_src[32 * MSTRIDE];
    __shared__ float s_w  [32 * MSTRIDE];

    if (tid < 128) {
        const int m4 = cb * 128 + tid;
        if (m4 < EPSZ / 4) {
            const int4 sv = reinterpret_cast<const int4*>(src_k)[m4];
            const int j = tid >> 2, i = (tid & 3) * 4;
            *reinterpret_cast<int4*>(&s_src[j * MSTRIDE + i]) = sv;
        }
    } else {
        const int t  = tid - 128;
        const int m4 = cb * 128 + t;
        if (m4 < EPSZ / 4) {
            const float4 wv = reinterpret_cast<const float4*>(w_k)[m4];
            const int j = t >> 2, i = (t & 3) * 4;
            *reinterpret_cast<float4*>(&s_w[j * MSTRIDE + i]) = wv;
        }
    }
    __syncthreads();

    const int wave = tid >> 6, lane = tid & 63;
    const int c2 = lane & 3;                   // col group (8 cols)
    const int eh = (lane >> 2) & 1;            // edge half
    const int q  = lane >> 3;                  // dest slot (0..7)
    const int j  = wave * 8 + q;               // dest within block (0..31)
    const int dest = cb * 32 + j;
    const int c8 = c2 * 8;

    if (dest < LEVEL) {
        const unsigned short* prev = hprev + (size_t)chunk * GENES * CCOLS;

        const int mb = j * MSTRIDE + eh * 8;
        const int4   sA = *reinterpret_cast<const int4*>  (&s_src[mb]);
        const int4   sB = *reinterpret_cast<const int4*>  (&s_src[mb + 4]);
        const float4 wA = *reinterpret_cast<const float4*>(&s_w  [mb]);
        const float4 wB = *reinterpret_cast<const float4*>(&s_w  [mb + 4]);

#define GL(sv) (*reinterpret_cast<const bf8*>(prev + (size_t)(sv) * CCOLS + c8))
        const bf8 v0 = GL(sA.x);
        const bf8 v1 = GL(sA.y);
        const bf8 v2 = GL(sA.z);
        const bf8 v3 = GL(sA.w);
        const bf8 v4 = GL(sB.x);
        const bf8 v5 = GL(sB.y);
        const bf8 v6 = GL(sB.z);
        const bf8 v7 = GL(sB.w);
#undef GL
        float a0 = 0.f, a1 = 0.f, a2 = 0.f, a3 = 0.f, a4 = 0.f, a5 = 0.f, a6 = 0.f, a7 = 0.f;
#define FMA8(v, wv) { a0 = fmaf(bf2f((v)[0]), (wv), a0); a1 = fmaf(bf2f((v)[1]), (wv), a1);  \
                      a2 = fmaf(bf2f((v)[2]), (wv), a2); a3 = fmaf(bf2f((v)[3]), (wv), a3);  \
                      a4 = fmaf(bf2f((v)[4]), (wv), a4); a5 = fmaf(bf2f((v)[5]), (wv), a5);  \
                      a6 = fmaf(bf2f((v)[6]), (wv), a6); a7 = fmaf(bf2f((v)[7]), (wv), a7); }
        FMA8(v0, wA.x) FMA8(v1, wA.y) FMA8(v2, wA.z) FMA8(v3, wA.w)
        FMA8(v4, wB.x) FMA8(v5, wB.y) FMA8(v6, wB.z) FMA8(v7, wB.w)
#undef FMA8
        a0 += __shfl_xor(a0, 4); a1 += __shfl_xor(a1, 4);
        a2 += __shfl_xor(a2, 4); a3 += __shfl_xor(a3, 4);
        a4 += __shfl_xor(a4, 4); a5 += __shfl_xor(a5, 4);
        a6 += __shfl_xor(a6, 4); a7 += __shfl_xor(a7, 4);

        if (eh == 0) {
            const float bz = node_bias[dstu_k[dest]];
            bf8 o;
            o[0] = f2bf(tanhf(a0 + bz));
            o[1] = f2bf(tanhf(a1 + bz));
            o[2] = f2bf(tanhf(a2 + bz));
            o[3] = f2bf(tanhf(a3 + bz));
            o[4] = f2bf(tanhf(a4 + bz));
            o[5] = f2bf(tanhf(a5 + bz));
            o[6] = f2bf(tanhf(a6 + bz));
            o[7] = f2bf(tanhf(a7 + bz));
            *reinterpret_cast<bf8*>(hcur + ((size_t)(chunk * 4 + c2) * LEVEL + dest) * SCOLS) = o;
        }
    }
}

// ---------------------------------------------------------------------------
// Staged step (k=1..5): block stages its colchunk's full prev slice in LDS
// (156.25 KiB), then each lane gathers its dests' 16 edges from LDS.
// bid mapping: colchunk c = (bid&7)*4 + ((bid>>3)&3); c>>2 == bid&7 == XCD.
// ---------------------------------------------------------------------------
__global__ __launch_bounds__(256, 1) void sstep_k(
        const unsigned short* __restrict__ hprev,   // [32][10000][8]
        unsigned short*       __restrict__ hcur,
        const unsigned short* __restrict__ srcT,    // [16][10000] this step
        const float*          __restrict__ wT,      // [16][10000]
        const float* __restrict__ node_bias,
        const int*   __restrict__ dstu_k) {
    __shared__ unsigned short slice[LEVEL * SCOLS];  // 160,000 B
    const int bid = blockIdx.x;
    const int c   = (bid & 7) * 4 + ((bid >> 3) & 3);
    const int g   = bid >> 5;
    const int tid = threadIdx.x;

    const unsigned short* pc = hprev + (size_t)c * LEVEL * SCOLS;
#pragma unroll 4
    for (int i = 0; i < 40; ++i) {
        const int row = i * 256 + tid;
        if (row < LEVEL)
            *reinterpret_cast<bf8*>(&slice[row * SCOLS]) =
                *reinterpret_cast<const bf8*>(pc + (size_t)row * SCOLS);
    }
    __syncthreads();

    unsigned short* oc = hcur + (size_t)c * LEVEL * SCOLS;
    const int dbeg = g * DPB, dend = dbeg + DPB;
    for (int d = dbeg + tid; d < dend; d += 256) {
        int   idx[DEG];
        float w[DEG];
#pragma unroll
        for (int e = 0; e < DEG; ++e) idx[e] = srcT[e * LEVEL + d];
#pragma unroll
        for (int e = 0; e < DEG; ++e) w[e] = wT[e * LEVEL + d];
        float a0 = 0.f, a1 = 0.f, a2 = 0.f, a3 = 0.f, a4 = 0.f, a5 = 0.f, a6 = 0.f, a7 = 0.f;
#pragma unroll
        for (int e = 0; e < DEG; ++e) {
            const bf8 v = *reinterpret_cast<const bf8*>(&slice[idx[e] * SCOLS]);
            a0 = fmaf(bf2f(v[0]), w[e], a0); a1 = fmaf(bf2f(v[1]), w[e], a1);
            a2 = fmaf(bf2f(v[2]), w[e], a2); a3 = fmaf(bf2f(v[3]), w[e], a3);
            a4 = fmaf(bf2f(v[4]), w[e], a4); a5 = fmaf(bf2f(v[5]), w[e], a5);
            a6 = fmaf(bf2f(v[6]), w[e], a6); a7 = fmaf(bf2f(v[7]), w[e], a7);
        }
        const float bz = node_bias[dstu_k[d]];
        bf8 o;
        o[0] = f2bf(tanhf(a0 + bz));
        o[1] = f2bf(tanhf(a1 + bz));
        o[2] = f2bf(tanhf(a2 + bz));
        o[3] = f2bf(tanhf(a3 + bz));
        o[4] = f2bf(tanhf(a4 + bz));
        o[5] = f2bf(tanhf(a5 + bz));
        o[6] = f2bf(tanhf(a6 + bz));
        o[7] = f2bf(tanhf(a7 + bz));
        *reinterpret_cast<bf8*>(oc + (size_t)d * SCOLS) = o;
    }
}

// ---------------------------------------------------------------------------
// Staged step 7 (k=6) fused with head: gathers as sstep_k; per-lane head
// accumulators h[8 cols][2]; fixed shfl tree + LDS wave combine -> part.
// ---------------------------------------------------------------------------
__global__ __launch_bounds__(256, 1) void sstep7_k(
        const unsigned short* __restrict__ hprev,
        const unsigned short* __restrict__ srcT,
        const float*          __restrict__ wT,
        const float* __restrict__ node_bias,
        const int*   __restrict__ dstu_k,
        const float* __restrict__ head_W,   // [LEVEL][2]
        float*       __restrict__ part) {   // [32][8][16]
    __shared__ unsigned short slice[LEVEL * SCOLS];
    __shared__ float scratch[4][16];
    const int bid = blockIdx.x;
    const int c   = (bid & 7) * 4 + ((bid >> 3) & 3);
    const int g   = bid >> 5;
    const int tid = threadIdx.x;

    const unsigned short* pc = hprev + (size_t)c * LEVEL * SCOLS;
#pragma unroll 4
    for (int i = 0; i < 40; ++i) {
        const int row = i * 256 + tid;
        if (row < LEVEL)
            *reinterpret_cast<bf8*>(&slice[row * SCOLS]) =
                *reinterpret_cast<const bf8*>(pc + (size_t)row * SCOLS);
    }
    __syncthreads();

    float h[16];
#pragma unroll
    for (int j = 0; j < 16; ++j) h[j] = 0.f;

    const int dbeg = g * DPB, dend = dbeg + DPB;
    for (int d = dbeg + tid; d < dend; d += 256) {
        int   idx[DEG];
        float w[DEG];
#pragma unroll
        for (int e = 0; e < DEG; ++e) idx[e] = srcT[e * LEVEL + d];
#pragma unroll
        for (int e = 0; e < DEG; ++e) w[e] = wT[e * LEVEL + d];
        float a0 = 0.f, a1 = 0.f, a2 = 0.f, a3 = 0.f, a4 = 0.f, a5 = 0.f, a6 = 0.f, a7 = 0.f;
#pragma unroll
        for (int e = 0; e < DEG; ++e) {
            const bf8 v = *reinterpret_cast<const bf8*>(&slice[idx[e] * SCOLS]);
            a0 = fmaf(bf2f(v[0]), w[e], a0); a1 = fmaf(bf2f(v[1]), w[e], a1);
            a2 = fmaf(bf2f(v[2]), w[e], a2); a3 = fmaf(bf2f(v[3]), w[e], a3);
            a4 = fmaf(bf2f(v[4]), w[e], a4); a5 = fmaf(bf2f(v[5]), w[e], a5);
            a6 = fmaf(bf2f(v[6]), w[e], a6); a7 = fmaf(bf2f(v[7]), w[e], a7);
        }
        const float bz = node_bias[dstu_k[d]];
        const float o0 = tanhf(a0 + bz), o1 = tanhf(a1 + bz);
        const float o2 = tanhf(a2 + bz), o3 = tanhf(a3 + bz);
        const float o4 = tanhf(a4 + bz), o5 = tanhf(a5 + bz);
        const float o6 = tanhf(a6 + bz), o7 = tanhf(a7 + bz);
        const float2 wv = *reinterpret_cast<const float2*>(head_W + (size_t)d * 2);
        h[0]  = fmaf(o0, wv.x, h[0]);  h[1]  = fmaf(o0, wv.y, h[1]);
        h[2]  = fmaf(o1, wv.x, h[2]);  h[3]  = fmaf(o1, wv.y, h[3]);
        h[4]  = fmaf(o2, wv.x, h[4]);  h[5]  = fmaf(o2, wv.y, h[5]);
        h[6]  = fmaf(o3, wv.x, h[6]);  h[7]  = fmaf(o3, wv.y, h[7]);
        h[8]  = fmaf(o4, wv.x, h[8]);  h[9]  = fmaf(o4, wv.y, h[9]);
        h[10] = fmaf(o5, wv.x, h[10]); h[11] = fmaf(o5, wv.y, h[11]);
        h[12] = fmaf(o6, wv.x, h[12]); h[13] = fmaf(o6, wv.y, h[13]);
        h[14] = fmaf(o7, wv.x, h[14]); h[15] = fmaf(o7, wv.y, h[15]);
    }

    const int wv_ = tid >> 6, lane = tid & 63;
#pragma unroll
    for (int m = 1; m < 64; m <<= 1) {
#pragma unroll
        for (int j = 0; j < 16; ++j) h[j] += __shfl_xor(h[j], m);
    }
    if (lane == 0) {
#pragma unroll
        for (int j = 0; j < 16; ++j) scratch[wv_][j] = h[j];
    }
    __syncthreads();
    if (tid < 16) {
        const float s = scratch[0][tid] + scratch[1][tid] + scratch[2][tid] + scratch[3][tid];
        part[((size_t)c * GPB + g) * 16 + tid] = s;
    }
}

// ---------------------------------------------------------------------------
// Head final: out[b][cc2] from 8 block-partials per colchunk (fixed order).
// ---------------------------------------------------------------------------
__global__ __launch_bounds__(512) void head_final_k(const float* __restrict__ part,
                                                    const float* __restrict__ head_b,
                                                    float*       __restrict__ out) {
    const int tid = threadIdx.x;             // 512 = 32 cc x 16 v
    const int cc = tid >> 4, v = tid & 15;
    float acc = head_b[v & 1];
#pragma unroll
    for (int g = 0; g < GPB; ++g)
        acc += part[((size_t)cc * GPB + g) * 16 + v];
    const int b = (cc >> 2) * 32 + (cc & 3) * 8 + (v >> 1);
    out[b * 2 + (v & 1)] = acc;
}

// ---------------------------------------------------------------------------
extern "C" void kernel_launch(void* const* d_in, const int* in_sizes, int n_in,
                              void* d_out, int out_size, void* d_ws, size_t ws_size,
                              hipStream_t stream) {
    const float* X           = (const float*)d_in[0];
    const float* edge_weight = (const float*)d_in[1];
    const float* node_bias   = (const float*)d_in[2];
    const float* head_W      = (const float*)d_in[3];
    const float* head_b      = (const float*)d_in[4];
    const int*   gene_map    = (const int*)  d_in[5];
    const int*   src         = (const int*)  d_in[6];
    /* d_in[7] = dst_pos: structurally repeat(arange(LEVEL),DEG) — encoded in layout */
    const int*   dst_unique  = (const int*)  d_in[8];
    /* d_in[9] = eid: structurally arange(E) — weights contiguous per step */
    /* d_in[10] = root_ids: structurally dst_unique[-1] — head fused into step 7 */
    float* out = (float*)d_out;

    // workspace layout (bytes)
    char* ws = (char*)d_ws;
    unsigned short* XT    = (unsigned short*)(ws);             // 8*20000*32*2  = 10,240,000
    unsigned short* lvlA  = (unsigned short*)(ws + 10240000);  // 32*10000*8*2  =  5,120,000
    unsigned short* lvlB  = (unsigned short*)(ws + 15360000);  //                  5,120,000
    unsigned short* srcT  = (unsigned short*)(ws + 20480000);  // 6*16*10000*2  =  1,920,000
    float*          wT    = (float*)         (ws + 22400000);  // 6*16*10000*4  =  3,840,000
    float*          part  = (float*)         (ws + 26240000);  // 32*8*16*4     =     16,384

    // 0) metadata transpose for staged steps (k=1..6)
    prep_k<<<dim3(40, 6), 256, 0, stream>>>(src, edge_weight, srcT, wT);

    // 1) transpose X into step1's 8-chunk layout
    transpose_k<<<dim3(NCHUNK, 157), 256, 0, stream>>>(X, gene_map, XT);

    // 2) step 1 (genes -> level 1), gather-style, writes staged layout
    step1_k<<<DBLK * NCHUNK, 256, 0, stream>>>(XT, lvlA, src, edge_weight,
                                               node_bias, dst_unique);

    // 3) steps 2..6 (k=1..5): LDS-staged
    unsigned short* bufs[2] = {lvlA, lvlB};
    for (int k = 1; k <= 5; ++k) {
        sstep_k<<<NCC * GPB, 256, 0, stream>>>(bufs[(k - 1) & 1], bufs[k & 1],
                                               srcT + (size_t)(k - 1) * DEG * LEVEL,
                                               wT   + (size_t)(k - 1) * DEG * LEVEL,
                                               node_bias,
                                               dst_unique + (size_t)k * LEVEL);
    }

    // 4) step 7 (k=6) staged + head partials, then tiny final
    sstep7_k<<<NCC * GPB, 256, 0, stream>>>(bufs[5 & 1], // lvlB
                                            srcT + (size_t)5 * DEG * LEVEL,
                                            wT   + (size_t)5 * DEG * LEVEL,
                                            node_bias,
                                            dst_unique + (size_t)6 * LEVEL,
                                            head_W, part);
    head_final_k<<<1, 512, 0, stream>>>(part, head_b, out);
    (void)in_sizes; (void)n_in; (void)out_size; (void)ws_size;
}

// Round 14
// 99.457 us; speedup vs baseline: 1.4944x; 1.4944x over previous
//
#include <hip/hip_runtime.h>
#include <math.h>

#define GENES 20000
#define LEVEL 10000
#define STEPS 7
#define DEG   16
#define EPSZ  (LEVEL * DEG)
#define CCOLS 64             // batch cols per chunk -> 128B rows (one full cache line)
#define NCHUNK 4             // 4 chunks; chunk = bid&3 -> XCDs {c, c+4}
#define SBLK7 313            // step7 blocks per chunk (32 dests each)
#define NGT   625            // gene tiles (20000/32)
#define MSTRIDE 18           // LDS metadata stride (16 + 2 pad)

typedef unsigned short bf8 __attribute__((ext_vector_type(8)));

__device__ inline float bf2f(unsigned short u) {
    union { unsigned u; float f; } c; c.u = ((unsigned)u) << 16; return c.f;
}
__device__ inline unsigned short f2bf(float x) {     // round-to-nearest-even
    union { float f; unsigned u; } c; c.f = x;
    return (unsigned short)((c.u + 0x7fffu + ((c.u >> 16) & 1u)) >> 16);
}

// ---------------------------------------------------------------------------
// Transpose X[b][g] (256 x 20000 fp32) -> XT[4 chunks][20000][64] bf16.
// grid (8 batch-tiles, 157): chunk = blockIdx.x>>1, col offset = (blockIdx.x&1)*32.
// ---------------------------------------------------------------------------
__global__ __launch_bounds__(256) void transpose_k(const float* __restrict__ X,
                                                   const int*   __restrict__ gene_map,
                                                   unsigned short* __restrict__ XT) {
    __shared__ float tile[32][33];
    const int bt   = blockIdx.x;                  // batch tile 0..7
    const int l4   = threadIdx.x & 7;
    const int r8   = threadIdx.x >> 3;
    const int lo   = threadIdx.x & 31;
    const int gr8  = threadIdx.x >> 5;
    const int chunk = bt >> 1;
    const int coff  = (bt & 1) * 32;
    unsigned short* XTp = XT + (size_t)chunk * GENES * CCOLS + coff;
    for (int i = 0; i < 4; ++i) {
        const int gt = blockIdx.y * 4 + i;
        if (gt >= NGT) break;
        const int g0 = gt * 32;
        if (i) __syncthreads();
        const float4 xv = *reinterpret_cast<const float4*>(
            X + (size_t)(bt * 32 + r8) * GENES + g0 + l4 * 4);
        tile[r8][l4 * 4 + 0] = xv.x;
        tile[r8][l4 * 4 + 1] = xv.y;
        tile[r8][l4 * 4 + 2] = xv.z;
        tile[r8][l4 * 4 + 3] = xv.w;
        __syncthreads();
#pragma unroll
        for (int jj = 0; jj < 4; ++jj) {
            const int gr   = gr8 + jj * 8;
            const int node = gene_map[g0 + gr];
            XTp[(size_t)node * CCOLS + lo] = f2bf(tile[lo][gr]);
        }
    }
}

// ---------------------------------------------------------------------------
// One DAG level (k = 0..5). Chunk planes have 128B rows: each edge gather is
// exactly ONE fully-used cache line. Wave = 4 dests x 2 edge-halves x 8
// col-lanes x 16B. Block = 16 dests; grid = 625 x 4 chunks (exact, no tails).
// ---------------------------------------------------------------------------
__global__ __launch_bounds__(256) void step_k(const unsigned short* __restrict__ hprev,
                                              unsigned short*       __restrict__ hcur,
                                              const int*   __restrict__ src_k,
                                              const float* __restrict__ w_k,
                                              const float* __restrict__ node_bias,
                                              const int*   __restrict__ dstu_k,
                                              int src_base, int prev_rows) {
    const int bid   = blockIdx.x;
    const int chunk = bid & 3;                 // -> XCDs {chunk, chunk+4}
    const int cb    = bid >> 2;                // 0..624
    const int tid   = threadIdx.x;

    __shared__ int   s_src[16 * MSTRIDE];
    __shared__ float s_w  [16 * MSTRIDE];

    // stage 16 dests' metadata: 256 edges = 64 int4 + 64 float4 (exact range)
    if (tid < 64) {
        const int4 sv = reinterpret_cast<const int4*>(src_k)[cb * 64 + tid];
        const int j = tid >> 2, i = (tid & 3) * 4;
        *reinterpret_cast<int4*>(&s_src[j * MSTRIDE + i]) = sv;
    } else if (tid < 128) {
        const int t = tid - 64;
        const float4 wv = reinterpret_cast<const float4*>(w_k)[cb * 64 + t];
        const int j = t >> 2, i = (t & 3) * 4;
        *reinterpret_cast<float4*>(&s_w[j * MSTRIDE + i]) = wv;
    }
    __syncthreads();

    const int wave = tid >> 6, lane = tid & 63;
    const int c16 = (lane & 7) * 8;            // col group: 8 bf16 = 16B of the 128B row
    const int eh  = (lane >> 3) & 1;           // edge half
    const int q   = lane >> 4;                 // dest slot (0..3)
    const int j   = wave * 4 + q;              // dest within block (0..15)
    const int dest = cb * 16 + j;              // < 10000 always (625*16 exact)

    const unsigned short* prev = hprev + (size_t)chunk * prev_rows * CCOLS;
    unsigned short*       curp = hcur + (size_t)chunk * LEVEL * CCOLS;

    const int mb = j * MSTRIDE + eh * 8;
    const int4   sA = *reinterpret_cast<const int4*>  (&s_src[mb]);
    const int4   sB = *reinterpret_cast<const int4*>  (&s_src[mb + 4]);
    const float4 wA = *reinterpret_cast<const float4*>(&s_w  [mb]);
    const float4 wB = *reinterpret_cast<const float4*>(&s_w  [mb + 4]);

#define GL(sv) (*reinterpret_cast<const bf8*>(prev + (size_t)((sv) - src_base) * CCOLS + c16))
    const bf8 v0 = GL(sA.x);
    const bf8 v1 = GL(sA.y);
    const bf8 v2 = GL(sA.z);
    const bf8 v3 = GL(sA.w);
    const bf8 v4 = GL(sB.x);
    const bf8 v5 = GL(sB.y);
    const bf8 v6 = GL(sB.z);
    const bf8 v7 = GL(sB.w);
#undef GL
    float a0 = 0.f, a1 = 0.f, a2 = 0.f, a3 = 0.f, a4 = 0.f, a5 = 0.f, a6 = 0.f, a7 = 0.f;
#define FMA8(v, wv) { a0 = fmaf(bf2f((v)[0]), (wv), a0); a1 = fmaf(bf2f((v)[1]), (wv), a1);  \
                      a2 = fmaf(bf2f((v)[2]), (wv), a2); a3 = fmaf(bf2f((v)[3]), (wv), a3);  \
                      a4 = fmaf(bf2f((v)[4]), (wv), a4); a5 = fmaf(bf2f((v)[5]), (wv), a5);  \
                      a6 = fmaf(bf2f((v)[6]), (wv), a6); a7 = fmaf(bf2f((v)[7]), (wv), a7); }
    FMA8(v0, wA.x) FMA8(v1, wA.y) FMA8(v2, wA.z) FMA8(v3, wA.w)
    FMA8(v4, wB.x) FMA8(v5, wB.y) FMA8(v6, wB.z) FMA8(v7, wB.w)
#undef FMA8

    // combine edge halves: partner lane = lane ^ 8 (same dest, same cols)
    a0 += __shfl_xor(a0, 8); a1 += __shfl_xor(a1, 8);
    a2 += __shfl_xor(a2, 8); a3 += __shfl_xor(a3, 8);
    a4 += __shfl_xor(a4, 8); a5 += __shfl_xor(a5, 8);
    a6 += __shfl_xor(a6, 8); a7 += __shfl_xor(a7, 8);

    if (eh == 0) {
        const float bz = node_bias[dstu_k[dest]];
        bf8 o;
        o[0] = f2bf(tanhf(a0 + bz));
        o[1] = f2bf(tanhf(a1 + bz));
        o[2] = f2bf(tanhf(a2 + bz));
        o[3] = f2bf(tanhf(a3 + bz));
        o[4] = f2bf(tanhf(a4 + bz));
        o[5] = f2bf(tanhf(a5 + bz));
        o[6] = f2bf(tanhf(a6 + bz));
        o[7] = f2bf(tanhf(a7 + bz));
        *reinterpret_cast<bf8*>(curp + (size_t)dest * CCOLS + c16) = o;
    }
}

// ---------------------------------------------------------------------------
// Step 7 (k=6) fused with head stage 1. Wave = 8 dests x 8 col-lanes; each
// lane: 16 sequential edge gathers (one 128B line each), tanh, x head_W ->
// h[16]; shfl tree over dest slots; LDS combine -> part[block][128].
// ---------------------------------------------------------------------------
__global__ __launch_bounds__(256) void step7_head_k(const unsigned short* __restrict__ hprev,
                                                    const int*   __restrict__ src_k,
                                                    const float* __restrict__ w_k,
                                                    const float* __restrict__ node_bias,
                                                    const int*   __restrict__ dstu_k,
                                                    const float* __restrict__ head_W, // [LEVEL][2]
                                                    float*       __restrict__ part,
                                                    int src_base) {
    const int bid   = blockIdx.x;
    const int chunk = bid & 3;
    const int cb    = bid >> 2;                // 0..312
    const int tid   = threadIdx.x;

    __shared__ int   s_src[32 * MSTRIDE];
    __shared__ float s_w  [32 * MSTRIDE];
    __shared__ float red[4][8][16];

    // stage 32 dests' metadata: 512 edges = 128 int4 + 128 float4 (guarded tail)
    if (tid < 128) {
        const int m4 = cb * 128 + tid;
        if (m4 < EPSZ / 4) {
            const int4 sv = reinterpret_cast<const int4*>(src_k)[m4];
            const int j = tid >> 2, i = (tid & 3) * 4;
            *reinterpret_cast<int4*>(&s_src[j * MSTRIDE + i]) = sv;
        }
    } else {
        const int t  = tid - 128;
        const int m4 = cb * 128 + t;
        if (m4 < EPSZ / 4) {
            const float4 wv = reinterpret_cast<const float4*>(w_k)[m4];
            const int j = t >> 2, i = (t & 3) * 4;
            *reinterpret_cast<float4*>(&s_w[j * MSTRIDE + i]) = wv;
        }
    }
    __syncthreads();

    const int wave = tid >> 6, lane = tid & 63;
    const int c16 = (lane & 7) * 8;            // col group (8 bf16)
    const int q   = lane >> 3;                 // dest slot (0..7)
    const int j   = wave * 8 + q;              // dest within block (0..31)
    const int dest = cb * 32 + j;

    const unsigned short* prev = hprev + (size_t)chunk * LEVEL * CCOLS;

    float h[16];
#pragma unroll
    for (int v = 0; v < 16; ++v) h[v] = 0.f;

    if (dest < LEVEL) {
        const int4   s0 = *reinterpret_cast<const int4*>  (&s_src[j * MSTRIDE + 0]);
        const int4   s1 = *reinterpret_cast<const int4*>  (&s_src[j * MSTRIDE + 4]);
        const int4   s2 = *reinterpret_cast<const int4*>  (&s_src[j * MSTRIDE + 8]);
        const int4   s3 = *reinterpret_cast<const int4*>  (&s_src[j * MSTRIDE + 12]);
        const float4 w0 = *reinterpret_cast<const float4*>(&s_w  [j * MSTRIDE + 0]);
        const float4 w1 = *reinterpret_cast<const float4*>(&s_w  [j * MSTRIDE + 4]);
        const float4 w2 = *reinterpret_cast<const float4*>(&s_w  [j * MSTRIDE + 8]);
        const float4 w3 = *reinterpret_cast<const float4*>(&s_w  [j * MSTRIDE + 12]);

        float a0 = 0.f, a1 = 0.f, a2 = 0.f, a3 = 0.f, a4 = 0.f, a5 = 0.f, a6 = 0.f, a7 = 0.f;
#define ACC(sv, wv) { const int idx = (sv) - src_base;                                      \
    const bf8 v = *reinterpret_cast<const bf8*>(prev + (size_t)idx * CCOLS + c16);          \
    a0 = fmaf(bf2f(v[0]), (wv), a0); a1 = fmaf(bf2f(v[1]), (wv), a1);                       \
    a2 = fmaf(bf2f(v[2]), (wv), a2); a3 = fmaf(bf2f(v[3]), (wv), a3);                       \
    a4 = fmaf(bf2f(v[4]), (wv), a4); a5 = fmaf(bf2f(v[5]), (wv), a5);                       \
    a6 = fmaf(bf2f(v[6]), (wv), a6); a7 = fmaf(bf2f(v[7]), (wv), a7); }
        ACC(s0.x, w0.x) ACC(s0.y, w0.y) ACC(s0.z, w0.z) ACC(s0.w, w0.w)
        ACC(s1.x, w1.x) ACC(s1.y, w1.y) ACC(s1.z, w1.z) ACC(s1.w, w1.w)
        ACC(s2.x, w2.x) ACC(s2.y, w2.y) ACC(s2.z, w2.z) ACC(s2.w, w2.w)
        ACC(s3.x, w3.x) ACC(s3.y, w3.y) ACC(s3.z, w3.z) ACC(s3.w, w3.w)
#undef ACC
        const float bz = node_bias[dstu_k[dest]];
        const float o0 = tanhf(a0 + bz), o1 = tanhf(a1 + bz);
        const float o2 = tanhf(a2 + bz), o3 = tanhf(a3 + bz);
        const float o4 = tanhf(a4 + bz), o5 = tanhf(a5 + bz);
        const float o6 = tanhf(a6 + bz), o7 = tanhf(a7 + bz);
        const float2 wv = *reinterpret_cast<const float2*>(head_W + (size_t)dest * 2);
        h[0]  = o0 * wv.x; h[1]  = o0 * wv.y;
        h[2]  = o1 * wv.x; h[3]  = o1 * wv.y;
        h[4]  = o2 * wv.x; h[5]  = o2 * wv.y;
        h[6]  = o3 * wv.x; h[7]  = o3 * wv.y;
        h[8]  = o4 * wv.x; h[9]  = o4 * wv.y;
        h[10] = o5 * wv.x; h[11] = o5 * wv.y;
        h[12] = o6 * wv.x; h[13] = o6 * wv.y;
        h[14] = o7 * wv.x; h[15] = o7 * wv.y;
    }

    // reduce over the wave's 8 dest slots (lane bits 3..5)
#pragma unroll
    for (int m = 8; m < 64; m <<= 1) {
#pragma unroll
        for (int v = 0; v < 16; ++v) h[v] += __shfl_xor(h[v], m);
    }
    if (lane < 8) {
#pragma unroll
        for (int v = 0; v < 16; ++v) red[wave][lane][v] = h[v];
    }
    __syncthreads();
    if (tid < 128) {
        const int cg = tid >> 4, v = tid & 15;
        const float s = red[0][cg][v] + red[1][cg][v] + red[2][cg][v] + red[3][cg][v];
        part[(size_t)bid * 128 + tid] = s;
    }
}

// ---------------------------------------------------------------------------
// Head final: out over 4 chunks x 64 cols x 2. part rows: bid = cb*4 + chunk.
// ---------------------------------------------------------------------------
__global__ __launch_bounds__(512) void head_final_k(const float* __restrict__ part,
                                                    const float* __restrict__ head_b,
                                                    float*       __restrict__ out) {
    const int tid = threadIdx.x;             // 512 = 4 chunks x 128
    const int chunk = tid >> 7, r = tid & 127;
    float acc = head_b[r & 1];
    for (int cb = 0; cb < SBLK7; ++cb)
        acc += part[(size_t)(cb * NCHUNK + chunk) * 128 + r];
    const int cg = r >> 4, v = r & 15;
    const int b = chunk * 64 + cg * 8 + (v >> 1);
    out[b * 2 + (v & 1)] = acc;
}

// ---------------------------------------------------------------------------
extern "C" void kernel_launch(void* const* d_in, const int* in_sizes, int n_in,
                              void* d_out, int out_size, void* d_ws, size_t ws_size,
                              hipStream_t stream) {
    const float* X           = (const float*)d_in[0];
    const float* edge_weight = (const float*)d_in[1];
    const float* node_bias   = (const float*)d_in[2];
    const float* head_W      = (const float*)d_in[3];
    const float* head_b      = (const float*)d_in[4];
    const int*   gene_map    = (const int*)  d_in[5];
    const int*   src         = (const int*)  d_in[6];
    /* d_in[7] = dst_pos: structurally repeat(arange(LEVEL),DEG) — encoded in layout */
    const int*   dst_unique  = (const int*)  d_in[8];
    /* d_in[9] = eid: structurally arange(E) — weights contiguous per step */
    /* d_in[10] = root_ids: structurally dst_unique[-1] — head fused into step 7 */
    float* out = (float*)d_out;

    // workspace layout (bytes)
    char* ws = (char*)d_ws;
    unsigned short* XT   = (unsigned short*)(ws);              // 4*20000*64*2 = 10,240,000
    unsigned short* lvlA = (unsigned short*)(ws + 10240000);   // 4*10000*64*2 =  5,120,000
    unsigned short* lvlB = (unsigned short*)(ws + 15360000);   //                 5,120,000
    float*          part = (float*)         (ws + 20480000);   // 1252*128*4   =    641,024

    // 1) transpose X into 4 chunked bf16 planes with 128B rows
    transpose_k<<<dim3(8, 157), 256, 0, stream>>>(X, gene_map, XT);

    // 2) levels 1..6 (k=0..5): one full cache line per edge gather
    unsigned short* bufs[2] = {lvlA, lvlB};
    for (int k = 0; k < STEPS - 1; ++k) {
        const unsigned short* hprev = (k == 0) ? XT : bufs[(k - 1) & 1];
        const int prevrows = (k == 0) ? GENES : LEVEL;
        const int srcbase  = (k == 0) ? 0 : GENES + (k - 1) * LEVEL;
        step_k<<<625 * NCHUNK, 256, 0, stream>>>(hprev, bufs[k & 1],
                                                 src + (size_t)k * EPSZ,
                                                 edge_weight + (size_t)k * EPSZ,
                                                 node_bias,
                                                 dst_unique + (size_t)k * LEVEL,
                                                 srcbase, prevrows);
    }

    // 3) level 7 fused with head partials, then tiny final
    {
        const int k = STEPS - 1;                            // 6
        const unsigned short* hprev = bufs[(k - 1) & 1];    // lvlB
        const int srcbase = GENES + (k - 1) * LEVEL;
        step7_head_k<<<SBLK7 * NCHUNK, 256, 0, stream>>>(hprev,
                                                         src + (size_t)k * EPSZ,
                                                         edge_weight + (size_t)k * EPSZ,
                                                         node_bias,
                                                         dst_unique + (size_t)k * LEVEL,
                                                         head_W, part, srcbase);
        head_final_k<<<1, 512, 0, stream>>>(part, head_b, out);
    }
    (void)in_sizes; (void)n_in; (void)out_size; (void)ws_size;
}

// Round 15
// 79.224 us; speedup vs baseline: 1.8761x; 1.2554x over previous
//
#include <hip/hip_runtime.h>
#include <math.h>

#define GENES 20000
#define LEVEL 10000
#define STEPS 7
#define DEG   16
#define EPSZ  (LEVEL * DEG)
#define CCOLS 32             // batch cols per step1 chunk
#define NCHUNK 8             // step1 chunks == XCDs
#define DBLK  313            // step1 blocks per chunk (32 dests each)
#define NGT   625            // gene tiles (20000/32)
#define MSTRIDE 18           // step1 LDS metadata stride
#define SCOLS 8              // staged colchunk width (bf16) -> 16B rows
#define DPG   1250           // dests per g-segment (10000/8)

typedef unsigned short bf8 __attribute__((ext_vector_type(8)));

__device__ inline float bf2f(unsigned short u) {
    union { unsigned u; float f; } c; c.u = ((unsigned)u) << 16; return c.f;
}
__device__ inline unsigned short f2bf(float x) {     // round-to-nearest-even
    union { float f; unsigned u; } c; c.f = x;
    return (unsigned short)((c.u + 0x7fffu + ((c.u >> 16) & 1u)) >> 16);
}

// ---------------------------------------------------------------------------
// Transpose X[b][g] (256 x 20000 fp32) -> XT[8 chunks][20000][32] bf16.
// ---------------------------------------------------------------------------
__global__ __launch_bounds__(256) void transpose_k(const float* __restrict__ X,
                                                   const int*   __restrict__ gene_map,
                                                   unsigned short* __restrict__ XT) {
    __shared__ float tile[32][33];
    const int chunk = blockIdx.x;
    const int l4  = threadIdx.x & 7;
    const int r8  = threadIdx.x >> 3;
    const int lo  = threadIdx.x & 31;
    const int gr8 = threadIdx.x >> 5;
    unsigned short* XTp = XT + (size_t)chunk * GENES * CCOLS;
    for (int i = 0; i < 4; ++i) {
        const int gt = blockIdx.y * 4 + i;
        if (gt >= NGT) break;
        const int g0 = gt * 32;
        if (i) __syncthreads();
        const float4 xv = *reinterpret_cast<const float4*>(
            X + (size_t)(chunk * CCOLS + r8) * GENES + g0 + l4 * 4);
        tile[r8][l4 * 4 + 0] = xv.x;
        tile[r8][l4 * 4 + 1] = xv.y;
        tile[r8][l4 * 4 + 2] = xv.z;
        tile[r8][l4 * 4 + 3] = xv.w;
        __syncthreads();
#pragma unroll
        for (int jj = 0; jj < 4; ++jj) {
            const int gr   = gr8 + jj * 8;
            const int node = gene_map[g0 + gr];
            XTp[(size_t)node * CCOLS + lo] = f2bf(tile[lo][gr]);
        }
    }
}

// ---------------------------------------------------------------------------
// Step 1 (k=0): genes source (320 KB > LDS), r11-style gather. Writes the
// staged layout hcur[32 cc][10000][8]; cc = chunk*4 + c2 (cc>>2 == XCD).
// ---------------------------------------------------------------------------
__global__ __launch_bounds__(256) void step1_k(const unsigned short* __restrict__ hprev,
                                               unsigned short*       __restrict__ hcur,
                                               const int*   __restrict__ src_k,
                                               const float* __restrict__ w_k,
                                               const float* __restrict__ node_bias,
                                               const int*   __restrict__ dstu_k) {
    const int bid   = blockIdx.x;
    const int chunk = bid & 7;
    const int cb    = bid >> 3;                // 0..312
    const int tid   = threadIdx.x;

    __shared__ int   s_src[32 * MSTRIDE];
    __shared__ float s_w  [32 * MSTRIDE];

    if (tid < 128) {
        const int m4 = cb * 128 + tid;
        if (m4 < EPSZ / 4) {
            const int4 sv = reinterpret_cast<const int4*>(src_k)[m4];
            const int j = tid >> 2, i = (tid & 3) * 4;
            *reinterpret_cast<int4*>(&s_src[j * MSTRIDE + i]) = sv;
        }
    } else {
        const int t  = tid - 128;
        const int m4 = cb * 128 + t;
        if (m4 < EPSZ / 4) {
            const float4 wv = reinterpret_cast<const float4*>(w_k)[m4];
            const int j = t >> 2, i = (t & 3) * 4;
            *reinterpret_cast<float4*>(&s_w[j * MSTRIDE + i]) = wv;
        }
    }
    __syncthreads();

    const int wave = tid >> 6, lane = tid & 63;
    const int c2 = lane & 3;                   // col group (8 cols)
    const int eh = (lane >> 2) & 1;            // edge half
    const int q  = lane >> 3;                  // dest slot (0..7)
    const int j  = wave * 8 + q;               // dest within block (0..31)
    const int dest = cb * 32 + j;
    const int c8 = c2 * 8;

    if (dest < LEVEL) {
        const unsigned short* prev = hprev + (size_t)chunk * GENES * CCOLS;

        const int mb = j * MSTRIDE + eh * 8;
        const int4   sA = *reinterpret_cast<const int4*>  (&s_src[mb]);
        const int4   sB = *reinterpret_cast<const int4*>  (&s_src[mb + 4]);
        const float4 wA = *reinterpret_cast<const float4*>(&s_w  [mb]);
        const float4 wB = *reinterpret_cast<const float4*>(&s_w  [mb + 4]);

#define GL(sv) (*reinterpret_cast<const bf8*>(prev + (size_t)(sv) * CCOLS + c8))
        const bf8 v0 = GL(sA.x);
        const bf8 v1 = GL(sA.y);
        const bf8 v2 = GL(sA.z);
        const bf8 v3 = GL(sA.w);
        const bf8 v4 = GL(sB.x);
        const bf8 v5 = GL(sB.y);
        const bf8 v6 = GL(sB.z);
        const bf8 v7 = GL(sB.w);
#undef GL
        float a0 = 0.f, a1 = 0.f, a2 = 0.f, a3 = 0.f, a4 = 0.f, a5 = 0.f, a6 = 0.f, a7 = 0.f;
#define FMA8(v, wv) { a0 = fmaf(bf2f((v)[0]), (wv), a0); a1 = fmaf(bf2f((v)[1]), (wv), a1);  \
                      a2 = fmaf(bf2f((v)[2]), (wv), a2); a3 = fmaf(bf2f((v)[3]), (wv), a3);  \
                      a4 = fmaf(bf2f((v)[4]), (wv), a4); a5 = fmaf(bf2f((v)[5]), (wv), a5);  \
                      a6 = fmaf(bf2f((v)[6]), (wv), a6); a7 = fmaf(bf2f((v)[7]), (wv), a7); }
        FMA8(v0, wA.x) FMA8(v1, wA.y) FMA8(v2, wA.z) FMA8(v3, wA.w)
        FMA8(v4, wB.x) FMA8(v5, wB.y) FMA8(v6, wB.z) FMA8(v7, wB.w)
#undef FMA8
        a0 += __shfl_xor(a0, 4); a1 += __shfl_xor(a1, 4);
        a2 += __shfl_xor(a2, 4); a3 += __shfl_xor(a3, 4);
        a4 += __shfl_xor(a4, 4); a5 += __shfl_xor(a5, 4);
        a6 += __shfl_xor(a6, 4); a7 += __shfl_xor(a7, 4);

        if (eh == 0) {
            const float bz = node_bias[dstu_k[dest]];
            bf8 o;
            o[0] = f2bf(tanhf(a0 + bz));
            o[1] = f2bf(tanhf(a1 + bz));
            o[2] = f2bf(tanhf(a2 + bz));
            o[3] = f2bf(tanhf(a3 + bz));
            o[4] = f2bf(tanhf(a4 + bz));
            o[5] = f2bf(tanhf(a5 + bz));
            o[6] = f2bf(tanhf(a6 + bz));
            o[7] = f2bf(tanhf(a7 + bz));
            *reinterpret_cast<bf8*>(hcur + ((size_t)(chunk * 4 + c2) * LEVEL + dest) * SCOLS) = o;
        }
    }
}

// ---------------------------------------------------------------------------
// Staged step (k=1..5): 1024-thread block (16 waves), 1 block/CU, 160 KB LDS
// slice. Metadata loaded per-thread (64B contiguous) BEFORE staging so 16
// waves hide the latency. cc = (bid&7)*4 + ((bid>>3)&3) -> cc>>2 == XCD.
// ---------------------------------------------------------------------------
__global__ __launch_bounds__(1024) void sstep_k(
        const unsigned short* __restrict__ hprev,   // [32][10000][8]
        unsigned short*       __restrict__ hcur,
        const int*   __restrict__ src_k,
        const float* __restrict__ w_k,
        const float* __restrict__ node_bias,
        const int*   __restrict__ dstu_k,
        int src_base) {
    __shared__ unsigned short slice[LEVEL * SCOLS];  // 160,000 B
    const int bid = blockIdx.x;
    const int cc  = (bid & 7) * 4 + ((bid >> 3) & 3);
    const int g   = bid >> 5;                  // 0..7
    const int tid = threadIdx.x;

    const int d0 = g * DPG + tid;              // always < LEVEL (tid < 1024 < 1250)
    const int be0 = d0 * DEG;
    const int4   sA = *reinterpret_cast<const int4*>  (src_k + be0);
    const int4   sB = *reinterpret_cast<const int4*>  (src_k + be0 + 4);
    const int4   sC = *reinterpret_cast<const int4*>  (src_k + be0 + 8);
    const int4   sD = *reinterpret_cast<const int4*>  (src_k + be0 + 12);
    const float4 wA = *reinterpret_cast<const float4*>(w_k + be0);
    const float4 wB = *reinterpret_cast<const float4*>(w_k + be0 + 4);
    const float4 wC = *reinterpret_cast<const float4*>(w_k + be0 + 8);
    const float4 wD = *reinterpret_cast<const float4*>(w_k + be0 + 12);

    // stage this cc's whole prev slice (coalesced 16B/thread)
    const unsigned short* pc = hprev + (size_t)cc * LEVEL * SCOLS;
#pragma unroll
    for (int i = 0; i < 10; ++i) {
        const int row = i * 1024 + tid;
        if (row < LEVEL)
            *reinterpret_cast<bf8*>(&slice[row * SCOLS]) =
                *reinterpret_cast<const bf8*>(pc + (size_t)row * SCOLS);
    }
    __syncthreads();

    unsigned short* oc = hcur + (size_t)cc * LEVEL * SCOLS;

#define ACC(sv, wv) { const int row = (sv) - src_base;                                      \
    const bf8 v = *reinterpret_cast<const bf8*>(&slice[row * SCOLS]);                       \
    a0 = fmaf(bf2f(v[0]), (wv), a0); a1 = fmaf(bf2f(v[1]), (wv), a1);                       \
    a2 = fmaf(bf2f(v[2]), (wv), a2); a3 = fmaf(bf2f(v[3]), (wv), a3);                       \
    a4 = fmaf(bf2f(v[4]), (wv), a4); a5 = fmaf(bf2f(v[5]), (wv), a5);                       \
    a6 = fmaf(bf2f(v[6]), (wv), a6); a7 = fmaf(bf2f(v[7]), (wv), a7); }

    {   // unit 0 (sequential e0..e15 — matches r10 numerics)
        float a0 = 0.f, a1 = 0.f, a2 = 0.f, a3 = 0.f, a4 = 0.f, a5 = 0.f, a6 = 0.f, a7 = 0.f;
        ACC(sA.x, wA.x) ACC(sA.y, wA.y) ACC(sA.z, wA.z) ACC(sA.w, wA.w)
        ACC(sB.x, wB.x) ACC(sB.y, wB.y) ACC(sB.z, wB.z) ACC(sB.w, wB.w)
        ACC(sC.x, wC.x) ACC(sC.y, wC.y) ACC(sC.z, wC.z) ACC(sC.w, wC.w)
        ACC(sD.x, wD.x) ACC(sD.y, wD.y) ACC(sD.z, wD.z) ACC(sD.w, wD.w)
        const float bz = node_bias[dstu_k[d0]];
        bf8 o;
        o[0] = f2bf(tanhf(a0 + bz));
        o[1] = f2bf(tanhf(a1 + bz));
        o[2] = f2bf(tanhf(a2 + bz));
        o[3] = f2bf(tanhf(a3 + bz));
        o[4] = f2bf(tanhf(a4 + bz));
        o[5] = f2bf(tanhf(a5 + bz));
        o[6] = f2bf(tanhf(a6 + bz));
        o[7] = f2bf(tanhf(a7 + bz));
        *reinterpret_cast<bf8*>(oc + (size_t)d0 * SCOLS) = o;
    }

    if (tid < DPG - 1024) {                    // unit 1 (226 threads)
        const int d1 = g * DPG + 1024 + tid;
        const int be1 = d1 * DEG;
        const int4   tA = *reinterpret_cast<const int4*>  (src_k + be1);
        const int4   tB = *reinterpret_cast<const int4*>  (src_k + be1 + 4);
        const int4   tC = *reinterpret_cast<const int4*>  (src_k + be1 + 8);
        const int4   tD = *reinterpret_cast<const int4*>  (src_k + be1 + 12);
        const float4 uA = *reinterpret_cast<const float4*>(w_k + be1);
        const float4 uB = *reinterpret_cast<const float4*>(w_k + be1 + 4);
        const float4 uC = *reinterpret_cast<const float4*>(w_k + be1 + 8);
        const float4 uD = *reinterpret_cast<const float4*>(w_k + be1 + 12);
        float a0 = 0.f, a1 = 0.f, a2 = 0.f, a3 = 0.f, a4 = 0.f, a5 = 0.f, a6 = 0.f, a7 = 0.f;
        ACC(tA.x, uA.x) ACC(tA.y, uA.y) ACC(tA.z, uA.z) ACC(tA.w, uA.w)
        ACC(tB.x, uB.x) ACC(tB.y, uB.y) ACC(tB.z, uB.z) ACC(tB.w, uB.w)
        ACC(tC.x, uC.x) ACC(tC.y, uC.y) ACC(tC.z, uC.z) ACC(tC.w, uC.w)
        ACC(tD.x, uD.x) ACC(tD.y, uD.y) ACC(tD.z, uD.z) ACC(tD.w, uD.w)
        const float bz = node_bias[dstu_k[d1]];
        bf8 o;
        o[0] = f2bf(tanhf(a0 + bz));
        o[1] = f2bf(tanhf(a1 + bz));
        o[2] = f2bf(tanhf(a2 + bz));
        o[3] = f2bf(tanhf(a3 + bz));
        o[4] = f2bf(tanhf(a4 + bz));
        o[5] = f2bf(tanhf(a5 + bz));
        o[6] = f2bf(tanhf(a6 + bz));
        o[7] = f2bf(tanhf(a7 + bz));
        *reinterpret_cast<bf8*>(oc + (size_t)d1 * SCOLS) = o;
    }
#undef ACC
}

// ---------------------------------------------------------------------------
// Staged step 7 (k=6) fused with head: tanh outputs -> x head_W -> per-thread
// h[16]; full-wave shfl tree + LDS wave combine -> part[cc*8+g][16].
// ---------------------------------------------------------------------------
__global__ __launch_bounds__(1024) void sstep7_k(
        const unsigned short* __restrict__ hprev,
        const int*   __restrict__ src_k,
        const float* __restrict__ w_k,
        const float* __restrict__ node_bias,
        const int*   __restrict__ dstu_k,
        const float* __restrict__ head_W,   // [LEVEL][2]
        float*       __restrict__ part,     // [32][8][16]
        int src_base) {
    __shared__ unsigned short slice[LEVEL * SCOLS];  // 160,000 B
    __shared__ float red[16][16];                    // 1 KB
    const int bid = blockIdx.x;
    const int cc  = (bid & 7) * 4 + ((bid >> 3) & 3);
    const int g   = bid >> 5;
    const int tid = threadIdx.x;

    const int d0 = g * DPG + tid;
    const int be0 = d0 * DEG;
    const int4   sA = *reinterpret_cast<const int4*>  (src_k + be0);
    const int4   sB = *reinterpret_cast<const int4*>  (src_k + be0 + 4);
    const int4   sC = *reinterpret_cast<const int4*>  (src_k + be0 + 8);
    const int4   sD = *reinterpret_cast<const int4*>  (src_k + be0 + 12);
    const float4 wA = *reinterpret_cast<const float4*>(w_k + be0);
    const float4 wB = *reinterpret_cast<const float4*>(w_k + be0 + 4);
    const float4 wC = *reinterpret_cast<const float4*>(w_k + be0 + 8);
    const float4 wD = *reinterpret_cast<const float4*>(w_k + be0 + 12);

    const unsigned short* pc = hprev + (size_t)cc * LEVEL * SCOLS;
#pragma unroll
    for (int i = 0; i < 10; ++i) {
        const int row = i * 1024 + tid;
        if (row < LEVEL)
            *reinterpret_cast<bf8*>(&slice[row * SCOLS]) =
                *reinterpret_cast<const bf8*>(pc + (size_t)row * SCOLS);
    }
    __syncthreads();

    float h[16];
#pragma unroll
    for (int v = 0; v < 16; ++v) h[v] = 0.f;

#define ACC(sv, wv) { const int row = (sv) - src_base;                                      \
    const bf8 v = *reinterpret_cast<const bf8*>(&slice[row * SCOLS]);                       \
    a0 = fmaf(bf2f(v[0]), (wv), a0); a1 = fmaf(bf2f(v[1]), (wv), a1);                       \
    a2 = fmaf(bf2f(v[2]), (wv), a2); a3 = fmaf(bf2f(v[3]), (wv), a3);                       \
    a4 = fmaf(bf2f(v[4]), (wv), a4); a5 = fmaf(bf2f(v[5]), (wv), a5);                       \
    a6 = fmaf(bf2f(v[6]), (wv), a6); a7 = fmaf(bf2f(v[7]), (wv), a7); }
#define HEADU(d) {                                                                           \
        const float bz = node_bias[dstu_k[d]];                                               \
        const float o0 = tanhf(a0 + bz), o1 = tanhf(a1 + bz);                                \
        const float o2 = tanhf(a2 + bz), o3 = tanhf(a3 + bz);                                \
        const float o4 = tanhf(a4 + bz), o5 = tanhf(a5 + bz);                                \
        const float o6 = tanhf(a6 + bz), o7 = tanhf(a7 + bz);                                \
        const float2 wv = *reinterpret_cast<const float2*>(head_W + (size_t)(d) * 2);        \
        h[0]  = fmaf(o0, wv.x, h[0]);  h[1]  = fmaf(o0, wv.y, h[1]);                         \
        h[2]  = fmaf(o1, wv.x, h[2]);  h[3]  = fmaf(o1, wv.y, h[3]);                         \
        h[4]  = fmaf(o2, wv.x, h[4]);  h[5]  = fmaf(o2, wv.y, h[5]);                         \
        h[6]  = fmaf(o3, wv.x, h[6]);  h[7]  = fmaf(o3, wv.y, h[7]);                         \
        h[8]  = fmaf(o4, wv.x, h[8]);  h[9]  = fmaf(o4, wv.y, h[9]);                         \
        h[10] = fmaf(o5, wv.x, h[10]); h[11] = fmaf(o5, wv.y, h[11]);                        \
        h[12] = fmaf(o6, wv.x, h[12]); h[13] = fmaf(o6, wv.y, h[13]);                        \
        h[14] = fmaf(o7, wv.x, h[14]); h[15] = fmaf(o7, wv.y, h[15]); }

    {
        float a0 = 0.f, a1 = 0.f, a2 = 0.f, a3 = 0.f, a4 = 0.f, a5 = 0.f, a6 = 0.f, a7 = 0.f;
        ACC(sA.x, wA.x) ACC(sA.y, wA.y) ACC(sA.z, wA.z) ACC(sA.w, wA.w)
        ACC(sB.x, wB.x) ACC(sB.y, wB.y) ACC(sB.z, wB.z) ACC(sB.w, wB.w)
        ACC(sC.x, wC.x) ACC(sC.y, wC.y) ACC(sC.z, wC.z) ACC(sC.w, wC.w)
        ACC(sD.x, wD.x) ACC(sD.y, wD.y) ACC(sD.z, wD.z) ACC(sD.w, wD.w)
        HEADU(d0)
    }
    if (tid < DPG - 1024) {
        const int d1 = g * DPG + 1024 + tid;
        const int be1 = d1 * DEG;
        const int4   tA = *reinterpret_cast<const int4*>  (src_k + be1);
        const int4   tB = *reinterpret_cast<const int4*>  (src_k + be1 + 4);
        const int4   tC = *reinterpret_cast<const int4*>  (src_k + be1 + 8);
        const int4   tD = *reinterpret_cast<const int4*>  (src_k + be1 + 12);
        const float4 uA = *reinterpret_cast<const float4*>(w_k + be1);
        const float4 uB = *reinterpret_cast<const float4*>(w_k + be1 + 4);
        const float4 uC = *reinterpret_cast<const float4*>(w_k + be1 + 8);
        const float4 uD = *reinterpret_cast<const float4*>(w_k + be1 + 12);
        float a0 = 0.f, a1 = 0.f, a2 = 0.f, a3 = 0.f, a4 = 0.f, a5 = 0.f, a6 = 0.f, a7 = 0.f;
        ACC(tA.x, uA.x) ACC(tA.y, uA.y) ACC(tA.z, uA.z) ACC(tA.w, uA.w)
        ACC(tB.x, uB.x) ACC(tB.y, uB.y) ACC(tB.z, uB.z) ACC(tB.w, uB.w)
        ACC(tC.x, uC.x) ACC(tC.y, uC.y) ACC(tC.z, uC.z) ACC(tC.w, uC.w)
        ACC(tD.x, uD.x) ACC(tD.y, uD.y) ACC(tD.z, uD.z) ACC(tD.w, uD.w)
        HEADU(d1)
    }
#undef HEADU
#undef ACC

    const int wave = tid >> 6, lane = tid & 63;
#pragma unroll
    for (int m = 1; m < 64; m <<= 1) {
#pragma unroll
        for (int v = 0; v < 16; ++v) h[v] += __shfl_xor(h[v], m);
    }
    if (lane == 0) {
#pragma unroll
        for (int v = 0; v < 16; ++v) red[wave][v] = h[v];
    }
    __syncthreads();
    if (tid < 16) {
        float s = 0.f;
#pragma unroll
        for (int w = 0; w < 16; ++w) s += red[w][tid];
        part[((size_t)cc * 8 + g) * 16 + tid] = s;
    }
}

// ---------------------------------------------------------------------------
// Head final: out from 8 g-partials per cc (fixed order).
// ---------------------------------------------------------------------------
__global__ __launch_bounds__(512) void head_final_k(const float* __restrict__ part,
                                                    const float* __restrict__ head_b,
                                                    float*       __restrict__ out) {
    const int tid = threadIdx.x;             // 512 = 32 cc x 16 v
    const int cc = tid >> 4, v = tid & 15;
    float acc = head_b[v & 1];
#pragma unroll
    for (int g = 0; g < 8; ++g)
        acc += part[((size_t)cc * 8 + g) * 16 + v];
    const int b = (cc >> 2) * 32 + (cc & 3) * 8 + (v >> 1);
    out[b * 2 + (v & 1)] = acc;
}

// ---------------------------------------------------------------------------
extern "C" void kernel_launch(void* const* d_in, const int* in_sizes, int n_in,
                              void* d_out, int out_size, void* d_ws, size_t ws_size,
                              hipStream_t stream) {
    const float* X           = (const float*)d_in[0];
    const float* edge_weight = (const float*)d_in[1];
    const float* node_bias   = (const float*)d_in[2];
    const float* head_W      = (const float*)d_in[3];
    const float* head_b      = (const float*)d_in[4];
    const int*   gene_map    = (const int*)  d_in[5];
    const int*   src         = (const int*)  d_in[6];
    /* d_in[7] = dst_pos: structurally repeat(arange(LEVEL),DEG) — encoded in layout */
    const int*   dst_unique  = (const int*)  d_in[8];
    /* d_in[9] = eid: structurally arange(E) — weights contiguous per step */
    /* d_in[10] = root_ids: structurally dst_unique[-1] — head fused into step 7 */
    float* out = (float*)d_out;

    // workspace layout (bytes)
    char* ws = (char*)d_ws;
    unsigned short* XT   = (unsigned short*)(ws);              // 8*20000*32*2 = 10,240,000
    unsigned short* lvlA = (unsigned short*)(ws + 10240000);   // 32*10000*8*2 =  5,120,000
    unsigned short* lvlB = (unsigned short*)(ws + 15360000);   //                 5,120,000
    float*          part = (float*)         (ws + 20480000);   // 32*8*16*4    =     16,384

    // 1) transpose X into step1's 8-chunk layout
    transpose_k<<<dim3(NCHUNK, 157), 256, 0, stream>>>(X, gene_map, XT);

    // 2) step 1 (genes -> level 1), gather-style, writes staged [32][10000][8]
    step1_k<<<DBLK * NCHUNK, 256, 0, stream>>>(XT, lvlA, src, edge_weight,
                                               node_bias, dst_unique);

    // 3) steps 2..6 (k=1..5): LDS-staged, 1 block/CU, 16 waves
    unsigned short* bufs[2] = {lvlA, lvlB};
    for (int k = 1; k <= 5; ++k) {
        sstep_k<<<256, 1024, 0, stream>>>(bufs[(k - 1) & 1], bufs[k & 1],
                                          src + (size_t)k * EPSZ,
                                          edge_weight + (size_t)k * EPSZ,
                                          node_bias,
                                          dst_unique + (size_t)k * LEVEL,
                                          GENES + (k - 1) * LEVEL);
    }

    // 4) step 7 (k=6) staged + head partials, then tiny final
    sstep7_k<<<256, 1024, 0, stream>>>(bufs[1], // lvlB
                                       src + (size_t)6 * EPSZ,
                                       edge_weight + (size_t)6 * EPSZ,
                                       node_bias,
                                       dst_unique + (size_t)6 * LEVEL,
                                       head_W, part,
                                       GENES + 5 * LEVEL);
    head_final_k<<<1, 512, 0, stream>>>(part, head_b, out);
    (void)in_sizes; (void)n_in; (void)out_size; (void)ws_size;
}